// Round 11
// baseline (258.369 us; speedup 1.0000x reference)
//
#include <hip/hip_runtime.h>
#include <hip/hip_bf16.h>

// Problem constants
#define BB 4
#define HH 8
#define SS 2048
#define HD 80
#define CC 128
#define NC 16
#define DH 480           // MULT*HD
#define NROW (BB*HH*SS)  // 65536
#define ROWSZ ((size_t)NROW * HD)  // 5,242,880 floats per tensor buffer

typedef unsigned short ushortT;
typedef __attribute__((ext_vector_type(8))) short bfrag;   // 8 bf16 = 4 VGPRs
typedef __attribute__((ext_vector_type(4))) float f4;
typedef __attribute__((ext_vector_type(4))) unsigned int u4;

__device__ __forceinline__ ushortT f2bf(float f) {
    __hip_bfloat16 h = __float2bfloat16(f);   // RNE
    ushortT u; __builtin_memcpy(&u, &h, 2); return u;
}
__device__ __forceinline__ float bf2f(ushortT u) {
    unsigned int x = ((unsigned int)u) << 16;
    float f; __builtin_memcpy(&f, &x, 4); return f;
}

// ---------------------------------------------------------------------------
// Kernel 0: prep — transpose + bf16-cast W1 (-> W1T[480][96], K zero-padded)
// and W2 (-> W2T[80][480]). Outputs live in d_out tail (k_mean overwrites last).
__global__ __launch_bounds__(256) void k_prep(const float* __restrict__ W1,
                                              const float* __restrict__ W2,
                                              ushortT* __restrict__ W1T,
                                              ushortT* __restrict__ W2T) {
    int idx = blockIdx.x * 256 + threadIdx.x;
    if (idx < 480 * 96) {
        int n = idx / 96, k = idx - n * 96;
        float v = (k < HD) ? W1[k * DH + n] : 0.f;
        W1T[idx] = f2bf(v);
    } else if (idx < 480 * 96 + 80 * 480) {
        int j = idx - 480 * 96;
        int n = j / DH, k = j - n * DH;
        W2T[j] = f2bf(W2[k * HD + n]);
    }
}

// ---------------------------------------------------------------------------
// Kernel 1: first LN. hdn stored as bf16 (every consumer casts to bf16 anyway);
// res stays fp32 (used in fp32 epilogue adds).
__global__ __launch_bounds__(256) void k_ln0(const float* __restrict__ x,
                                             const float* __restrict__ g,
                                             const float* __restrict__ be,
                                             ushortT* __restrict__ hdnb,
                                             float* __restrict__ res) {
    int row  = blockIdx.x * 4 + (threadIdx.x >> 6);
    int lane = threadIdx.x & 63;
    const float* xr = x + (size_t)row * HD;
    float v0 = xr[lane];
    float v1 = (lane < 16) ? xr[64 + lane] : 0.f;
    float s  = v0 + v1;
    float sq = v0 * v0 + v1 * v1;
#pragma unroll
    for (int o = 32; o; o >>= 1) { s += __shfl_xor(s, o); sq += __shfl_xor(sq, o); }
    float m    = s * (1.f / 80.f);
    float var  = sq * (1.f / 80.f) - m * m;
    float rstd = rsqrtf(var + 1e-5f);
    size_t base = (size_t)row * HD;
    float y0 = (v0 - m) * rstd * g[lane] + be[lane];
    hdnb[base + lane] = f2bf(y0); res[base + lane] = y0;
    if (lane < 16) {
        float y1 = (v1 - m) * rstd * g[64 + lane] + be[64 + lane];
        hdnb[base + 64 + lane] = f2bf(y1); res[base + 64 + lane] = y1;
    }
}

// ---------------------------------------------------------------------------
// Kernel 2: per-chunk intra attention + chunk KV, all via bf16 MFMA.
__global__ __launch_bounds__(256) void k_attn_a(const ushortT* __restrict__ hdn,
                                                const float* __restrict__ slopes,
                                                float* __restrict__ oin,
                                                float* __restrict__ ckv) {
    __shared__ ushortT Xs[CC * 104];   // 128 rows x 96(k-pad, stride 104)
    __shared__ ushortT SC[CC * 40];    // 128 rows x 32(pad 40) score block, A-layout
    __shared__ ushortT XT[HD * 136];   // 80 d-rows x 128 j (stride 136)
    __shared__ float dec[CC];          // exp(-sl*delta)
    __shared__ float sqk[CC];          // sqrt(kd[j]) = exp(-0.5*sl*(128-j))

    int t    = threadIdx.x;
    int wave = t >> 6, lane = t & 63;
    int quad = lane >> 4, ln16 = lane & 15;
    int bk = blockIdx.x;
    int bh = bk >> 4;
    int n  = bk & 15;
    float sl = slopes[bh & 7];

    size_t chunkrow = (size_t)bh * SS + (size_t)n * CC;
    const ushortT* xb = hdn + chunkrow * HD;

    if (t < CC) {
        dec[t] = expf(-sl * (float)t);
        sqk[t] = expf(-0.5f * sl * (float)(CC - t));
    }
    for (int u = t; u < CC * HD; u += 256) {
        int i = u / HD, c = u - i * HD;
        ushortT v = xb[u];
        Xs[i * 104 + c] = v;
        XT[c * 136 + i] = v;
    }
    for (int u = t; u < CC * 16; u += 256) {
        int i = u >> 4, c = u & 15;
        Xs[i * 104 + 80 + c] = 0;
    }
    __syncthreads();

    bfrag a[2][3];
#pragma unroll
    for (int rt = 0; rt < 2; ++rt) {
        int mt = wave + rt * 4;
#pragma unroll
        for (int ks = 0; ks < 3; ++ks)
            a[rt][ks] = *(const bfrag*)&Xs[(mt * 16 + ln16) * 104 + ks * 32 + quad * 8];
    }

    f4 oacc[2][5];
#pragma unroll
    for (int rt = 0; rt < 2; ++rt)
#pragma unroll
        for (int ot = 0; ot < 5; ++ot) oacc[rt][ot] = (f4)0.f;

    for (int jt = 0; jt < 4; ++jt) {
        if (wave + 4 < 2 * jt) continue;
        int j0 = jt * 32;
        bfrag bq[2][3];
#pragma unroll
        for (int nt = 0; nt < 2; ++nt)
#pragma unroll
            for (int ks = 0; ks < 3; ++ks)
                bq[nt][ks] = *(const bfrag*)&Xs[(j0 + nt * 16 + ln16) * 104 + ks * 32 + quad * 8];

#pragma unroll
        for (int rt = 0; rt < 2; ++rt) {
            int mt = wave + rt * 4;
            if (mt < 2 * jt) continue;
            int i_base = mt * 16;
            f4 c0 = (f4)0.f, c1 = (f4)0.f;
#pragma unroll
            for (int ks = 0; ks < 3; ++ks) {
                c0 = __builtin_amdgcn_mfma_f32_16x16x32_bf16(a[rt][ks], bq[0][ks], c0, 0, 0, 0);
                c1 = __builtin_amdgcn_mfma_f32_16x16x32_bf16(a[rt][ks], bq[1][ks], c1, 0, 0, 0);
            }
#pragma unroll
            for (int r = 0; r < 4; ++r) {
                int i = i_base + quad * 4 + r;
                int d0 = i - (j0 + ln16);
                int d1 = d0 - 16;
                float f0 = (d0 >= 0) ? dec[d0] : 0.f;
                float f1 = (d1 >= 0) ? dec[d1] : 0.f;
                SC[i * 40 + ln16]      = f2bf(c0[r] * f0);
                SC[i * 40 + 16 + ln16] = f2bf(c1[r] * f1);
            }
            bfrag a2 = *(const bfrag*)&SC[(i_base + ln16) * 40 + quad * 8];
#pragma unroll
            for (int ot = 0; ot < 5; ++ot) {
                bfrag bv = *(const bfrag*)&XT[(ot * 16 + ln16) * 136 + j0 + quad * 8];
                oacc[rt][ot] = __builtin_amdgcn_mfma_f32_16x16x32_bf16(a2, bv, oacc[rt][ot], 0, 0, 0);
            }
        }
    }

#pragma unroll
    for (int rt = 0; rt < 2; ++rt) {
        int i_base = (wave + rt * 4) * 16;
#pragma unroll
        for (int r = 0; r < 4; ++r) {
            size_t grow = (chunkrow + i_base + quad * 4 + r) * HD;
#pragma unroll
            for (int ot = 0; ot < 5; ++ot)
                oin[grow + ot * 16 + ln16] = oacc[rt][ot][r];
        }
    }

    __syncthreads();
    for (int u = t; u < HD * CC; u += 256) {
        int e = u >> 7, j = u & 127;
        int idx = e * 136 + j;
        XT[idx] = f2bf(bf2f(XT[idx]) * sqk[j]);
    }
    __syncthreads();

    float* kvout = ckv + (size_t)bk * (HD * HD);
    for (int p = wave; p < 25; p += 4) {
        int me = p / 5, ne = p - me * 5;
        f4 c = (f4)0.f;
#pragma unroll
        for (int ks = 0; ks < 4; ++ks) {
            bfrag av = *(const bfrag*)&XT[(me * 16 + ln16) * 136 + ks * 32 + quad * 8];
            bfrag bv = *(const bfrag*)&XT[(ne * 16 + ln16) * 136 + ks * 32 + quad * 8];
            c = __builtin_amdgcn_mfma_f32_16x16x32_bf16(av, bv, c, 0, 0, 0);
        }
#pragma unroll
        for (int r = 0; r < 4; ++r)
            kvout[(me * 16 + quad * 4 + r) * HD + ne * 16 + ln16] = c[r];
    }
}

// ---------------------------------------------------------------------------
// Kernel 4: inter-chunk term via bf16 MFMA, fused + intra + residual + LN.
// k_scan is GONE: the KV prefix state for chunk n is computed inline via the
// same Horner recurrence (acc = bd*acc + ckv[m], m=0..n-1) — identical float
// sequence to the old scan. 7 f4 register accumulators/thread, coalesced f4
// loads (ckv is L3-resident), KVT staged transposed from registers.
__global__ __launch_bounds__(256) void k_attn_b(const ushortT* __restrict__ hdn_in,
                                                const float* __restrict__ oin,
                                                const float* __restrict__ ckv,
                                                const float* __restrict__ res,
                                                const float* __restrict__ slopes,
                                                const float* __restrict__ g,
                                                const float* __restrict__ be,
                                                ushortT* __restrict__ hdn_out) {
    __shared__ ushortT Qs[CC * 104];     // 128 rows x (96 k, padded stride 104)
    __shared__ ushortT KVT[80 * 104];    // 80 d-rows x (96 e, padded stride 104)

    int t    = threadIdx.x;
    int wave = t >> 6, lane = t & 63;
    int qd   = lane >> 4, ln16 = lane & 15;
    int bk = blockIdx.x;
    int bh = bk >> 4;
    int n  = bk & 15;
    float sl = slopes[bh & 7];

    size_t chunkrow = (size_t)bh * SS + (size_t)n * CC;
    const ushortT* xb = hdn_in + chunkrow * HD;

    // Q staging: rows are 10 u4 (160B) each; Qs stride 104 ushorts = 13 u4.
    {
        const u4* xin = (const u4*)xb;
        u4* Qs4 = (u4*)Qs;
        for (int u = t; u < CC * 10; u += 256) {
            int i = u / 10, c = u - i * 10;
            Qs4[i * 13 + c] = xin[u];
        }
        for (int u = t; u < CC * 16; u += 256) {
            int i = u >> 4, c = u & 15;
            Qs[i * 104 + 80 + c] = 0;
        }
    }

    // Inline KV prefix (Horner, bit-identical to the old k_scan recurrence).
    // 6400 floats = 1600 f4; thread t owns f4 indices {t, t+256, ..., t+1536}.
    {
        float bd = expf(-sl * (float)CC);
        f4 acc4[7];
#pragma unroll
        for (int k = 0; k < 7; ++k) acc4[k] = (f4)0.f;
        const f4* cb = (const f4*)(ckv + (size_t)bh * NC * (HD * HD));
        for (int m = 0; m < n; ++m) {
            const f4* cm = cb + (size_t)m * 1600;
#pragma unroll
            for (int k = 0; k < 7; ++k) {
                int u = t + 256 * k;
                if (u < 1600) acc4[k] = bd * acc4[k] + cm[u];
            }
        }
        // stage KVT transposed: element j = 4u+z -> (e = j/80, d = j%80)
#pragma unroll
        for (int k = 0; k < 7; ++k) {
            int u = t + 256 * k;
            if (u < 1600) {
                int jb = u * 4;
#pragma unroll
                for (int z = 0; z < 4; ++z) {
                    int j = jb + z, e = j / 80, d = j - e * 80;
                    KVT[d * 104 + e] = f2bf(acc4[k][z]);
                }
            }
        }
        for (int u = t; u < HD * 16; u += 256) {
            int d = u >> 4, e = u & 15;
            KVT[d * 104 + 80 + e] = 0;
        }
    }
    __syncthreads();

    int m0 = wave * 32;
    bfrag a[2][3];
#pragma unroll
    for (int rt = 0; rt < 2; ++rt)
#pragma unroll
        for (int ks = 0; ks < 3; ++ks)
            a[rt][ks] = *(const bfrag*)&Qs[(m0 + rt * 16 + ln16) * 104 + ks * 32 + qd * 8];

    f4 acc[2][5];
#pragma unroll
    for (int ot = 0; ot < 5; ++ot) {
#pragma unroll
        for (int rt = 0; rt < 2; ++rt) acc[rt][ot] = (f4)0.f;
#pragma unroll
        for (int ks = 0; ks < 3; ++ks) {
            bfrag b = *(const bfrag*)&KVT[(ot * 16 + ln16) * 104 + ks * 32 + qd * 8];
#pragma unroll
            for (int rt = 0; rt < 2; ++rt)
                acc[rt][ot] = __builtin_amdgcn_mfma_f32_16x16x32_bf16(a[rt][ks], b, acc[rt][ot], 0, 0, 0);
        }
    }

#pragma unroll
    for (int rt = 0; rt < 2; ++rt) {
#pragma unroll
        for (int r = 0; r < 4; ++r) {
            int i = m0 + rt * 16 + qd * 4 + r;
            float qdec = expf(-sl * (float)i);
            size_t grow = (chunkrow + i) * HD;
            float tv[5];
            float s = 0.f, sq = 0.f;
#pragma unroll
            for (int ot = 0; ot < 5; ++ot) {
                int col = ot * 16 + ln16;
                tv[ot] = oin[grow + col] + qdec * acc[rt][ot][r] + res[grow + col];
                s += tv[ot]; sq += tv[ot] * tv[ot];
            }
#pragma unroll
            for (int o = 8; o; o >>= 1) { s += __shfl_xor(s, o); sq += __shfl_xor(sq, o); }
            float m    = s * (1.f / 80.f);
            float var  = sq * (1.f / 80.f) - m * m;
            float rstd = rsqrtf(var + 1e-5f);
#pragma unroll
            for (int ot = 0; ot < 5; ++ot) {
                int col = ot * 16 + ln16;
                hdn_out[grow + col] = f2bf((tv[ot] - m) * rstd * g[col] + be[col]);
            }
        }
    }
}

// ---------------------------------------------------------------------------
// Kernel 5: FFN via bf16 MFMA, 128 rows/block. Input bf16 (u4-copy staging).
// Output: bf16 (iter 0, consumed by attn kernels) or fp32 (iter 1, k_mean).
__global__ __launch_bounds__(256, 2) void k_ffn(const ushortT* __restrict__ hdn_in,
                                                const ushortT* __restrict__ W1T,
                                                const float* __restrict__ b1,
                                                const ushortT* __restrict__ W2T,
                                                const float* __restrict__ b2,
                                                const float* __restrict__ res,
                                                const float* __restrict__ g,
                                                const float* __restrict__ be,
                                                ushortT* __restrict__ outb,
                                                float* __restrict__ outf,
                                                int write_f32) {
    __shared__ ushortT Xs[128 * 104];    // 26.6 KB: X tile, K padded 80->96
    __shared__ ushortT WH[128 * 104];    // 26.6 KB: W1 tile (rows 0..95) / Hs alias
    __shared__ ushortT W2s[80 * 104];    // 16.6 KB
    // total 69.9 KB -> 2 blocks/CU

    int t    = threadIdx.x;
    int wave = t >> 6, lane = t & 63;
    int qd   = lane >> 4, ln16 = lane & 15;
    size_t rowbase = (size_t)blockIdx.x * 128;

    // stage X: pure u4 copy (rows = 10 u4 of bf16; Xs stride 13 u4)
    {
        const u4* xin = (const u4*)(hdn_in + rowbase * HD);
        u4* Xs4 = (u4*)Xs;
        for (int u = t; u < 128 * 10; u += 256) {
            int i = u / 10, c = u - i * 10;
            Xs4[i * 13 + c] = xin[u];
        }
        for (int u = t; u < 128 * 16; u += 256) {
            int i = u >> 4, c = u & 15;
            Xs[i * 104 + 80 + c] = 0;
        }
    }

    f4 acc[2][5];
#pragma unroll
    for (int rt = 0; rt < 2; ++rt)
#pragma unroll
        for (int ot = 0; ot < 5; ++ot) acc[rt][ot] = (f4)0.f;

    const u4* W1T16 = (const u4*)W1T;    // 480 rows x 12 u4
    const u4* W2T16 = (const u4*)W2T;    // 80 rows x 60 u4
    u4* WH16  = (u4*)WH;                 // row stride 13 u4 (=104 ushort)
    u4* W2s16 = (u4*)W2s;

    for (int jt = 0; jt < DH; jt += 96) {
        __syncthreads();   // protects Xs (iter 0) / WH+W2s from previous iter reads
        for (int u = t; u < 96 * 12; u += 256) {
            int n = u / 12, k = u - n * 12;
            WH16[n * 13 + k] = W1T16[(size_t)(jt + n) * 12 + k];
        }
        for (int u = t; u < 80 * 12; u += 256) {
            int n = u / 12, k = u - n * 12;
            W2s16[n * 13 + k] = W2T16[(size_t)n * 60 + (jt >> 3) + k];
        }
        __syncthreads();

        // GEMM1: H chunk = X @ W1c. Each wave: 2 m-tiles (rows wave*32..+31)
        f4 hc[2][6];
#pragma unroll
        for (int rt = 0; rt < 2; ++rt)
#pragma unroll
            for (int nt = 0; nt < 6; ++nt) hc[rt][nt] = (f4)0.f;
#pragma unroll
        for (int ks = 0; ks < 3; ++ks) {
            bfrag a0 = *(const bfrag*)&Xs[((wave * 2 + 0) * 16 + ln16) * 104 + ks * 32 + qd * 8];
            bfrag a1 = *(const bfrag*)&Xs[((wave * 2 + 1) * 16 + ln16) * 104 + ks * 32 + qd * 8];
#pragma unroll
            for (int nt = 0; nt < 6; ++nt) {
                bfrag b = *(const bfrag*)&WH[(nt * 16 + ln16) * 104 + ks * 32 + qd * 8];
                hc[0][nt] = __builtin_amdgcn_mfma_f32_16x16x32_bf16(a0, b, hc[0][nt], 0, 0, 0);
                hc[1][nt] = __builtin_amdgcn_mfma_f32_16x16x32_bf16(a1, b, hc[1][nt], 0, 0, 0);
            }
        }
        __syncthreads();   // all waves done reading W1 tile (WH) before Hs overwrite

        // leaky-relu + bf16 -> Hs (aliases WH; rows wave-private)
#pragma unroll
        for (int rt = 0; rt < 2; ++rt) {
            int mrow = (wave * 2 + rt) * 16 + qd * 4;
#pragma unroll
            for (int nt = 0; nt < 6; ++nt) {
                float bv = b1[jt + nt * 16 + ln16];
#pragma unroll
                for (int r = 0; r < 4; ++r) {
                    float v = hc[rt][nt][r] + bv;
                    v = (v > 0.f) ? v : 0.01f * v;
                    WH[(mrow + r) * 104 + nt * 16 + ln16] = f2bf(v);
                }
            }
        }
        // GEMM2: acc += H chunk @ W2c (no barrier: Hs rows written by this wave)
#pragma unroll
        for (int ks = 0; ks < 3; ++ks) {
            bfrag a0 = *(const bfrag*)&WH[((wave * 2 + 0) * 16 + ln16) * 104 + ks * 32 + qd * 8];
            bfrag a1 = *(const bfrag*)&WH[((wave * 2 + 1) * 16 + ln16) * 104 + ks * 32 + qd * 8];
#pragma unroll
            for (int ot = 0; ot < 5; ++ot) {
                bfrag b = *(const bfrag*)&W2s[(ot * 16 + ln16) * 104 + ks * 32 + qd * 8];
                acc[0][ot] = __builtin_amdgcn_mfma_f32_16x16x32_bf16(a0, b, acc[0][ot], 0, 0, 0);
                acc[1][ot] = __builtin_amdgcn_mfma_f32_16x16x32_bf16(a1, b, acc[1][ot], 0, 0, 0);
            }
        }
    }

    // epilogue: + b2 + residual, LN per row (C-layout: row=qd*4+r, col=ot*16+ln16)
#pragma unroll
    for (int rt = 0; rt < 2; ++rt) {
        int mbase = (wave * 2 + rt) * 16 + qd * 4;
#pragma unroll
        for (int r = 0; r < 4; ++r) {
            size_t row = rowbase + mbase + r;
            float tv[5];
            float s = 0.f, sq = 0.f;
#pragma unroll
            for (int ot = 0; ot < 5; ++ot) {
                int col = ot * 16 + ln16;
                tv[ot] = acc[rt][ot][r] + b2[col] + res[row * HD + col];
                s += tv[ot]; sq += tv[ot] * tv[ot];
            }
#pragma unroll
            for (int o = 8; o; o >>= 1) { s += __shfl_xor(s, o); sq += __shfl_xor(sq, o); }
            float m    = s * (1.f / 80.f);
            float var  = sq * (1.f / 80.f) - m * m;
            float rstd = rsqrtf(var + 1e-5f);
            if (write_f32) {
#pragma unroll
                for (int ot = 0; ot < 5; ++ot) {
                    int col = ot * 16 + ln16;
                    outf[row * HD + col] = (tv[ot] - m) * rstd * g[col] + be[col];
                }
            } else {
#pragma unroll
                for (int ot = 0; ot < 5; ++ot) {
                    int col = ot * 16 + ln16;
                    outb[row * HD + col] = f2bf((tv[ot] - m) * rstd * g[col] + be[col]);
                }
            }
        }
    }
}

// ---------------------------------------------------------------------------
// Kernel 6: mean over heads -> (B, S, HD). f4-vectorized.
__global__ __launch_bounds__(256) void k_mean(const float* __restrict__ hdn,
                                              float* __restrict__ out) {
    int idx = blockIdx.x * 256 + threadIdx.x;      // < BB*SS*HD/4
    int b   = idx / (SS * HD / 4);
    int sd  = idx - b * (SS * HD / 4);
    const f4* hp = (const f4*)hdn;
    f4 s = (f4)0.f;
#pragma unroll
    for (int h = 0; h < HH; ++h) {
        f4 v = hp[(size_t)(b * HH + h) * (SS * HD / 4) + sd];
        s = s + v;
    }
    ((f4*)out)[idx] = s * 0.125f;
}

// ---------------------------------------------------------------------------
extern "C" void kernel_launch(void* const* d_in, const int* in_sizes, int n_in,
                              void* d_out, int out_size, void* d_ws, size_t ws_size,
                              hipStream_t stream) {
    (void)in_sizes; (void)n_in; (void)out_size; (void)ws_size;
    const float* x      = (const float*)d_in[0];
    const float* W1     = (const float*)d_in[1];
    const float* b1     = (const float*)d_in[2];
    const float* W2     = (const float*)d_in[3];
    const float* b2     = (const float*)d_in[4];
    const float* gamma  = (const float*)d_in[5];
    const float* beta   = (const float*)d_in[6];
    const float* slopes = (const float*)d_in[7];
    float* out = (float*)d_out;
    float* ws  = (float*)d_ws;

    float*   res  = ws;                          // fp32, 5,242,880 floats
    ushortT* hdnb = (ushortT*)(ws + ROWSZ);      // bf16 hdn intermediates
    float*   oin  = ws + 2 * ROWSZ;              // fp32 (precision-critical)
    float*   ckv  = ws + 3 * ROWSZ;              // fp32 per-chunk Gram matrices
    float*   hdnf = ws + 4 * ROWSZ;              // fp32 final (k_mean input)

    // bf16 transposed weights live in d_out scratch (k_mean overwrites it last)
    ushortT* W1T = (ushortT*)d_out;              // 480*96
    ushortT* W2T = W1T + 480 * 96;               // 80*480

    k_prep<<<(480 * 96 + 80 * 480 + 255) / 256, 256, 0, stream>>>(W1, W2, W1T, W2T);
    k_ln0<<<NROW / 4, 256, 0, stream>>>(x, gamma, beta, hdnb, res);
    for (int it = 0; it < 2; ++it) {
        k_attn_a<<<BB * HH * NC, 256, 0, stream>>>(hdnb, slopes, oin, ckv);
        k_attn_b<<<BB * HH * NC, 256, 0, stream>>>(hdnb, oin, ckv, res, slopes, gamma, beta, hdnb);
        k_ffn<<<NROW / 128, 256, 0, stream>>>(hdnb, W1T, b1, W2T, b2, res, gamma, beta,
                                              hdnb, hdnf, (it == 1) ? 1 : 0);
    }
    k_mean<<<(BB * SS * HD) / (256 * 4), 256, 0, stream>>>(hdnf, out);
}

// Round 14
// 232.787 us; speedup vs baseline: 1.1099x; 1.1099x over previous
//
#include <hip/hip_runtime.h>
#include <hip/hip_bf16.h>

// Problem constants
#define BB 4
#define HH 8
#define SS 2048
#define HD 80
#define CC 128
#define NC 16
#define DH 480           // MULT*HD
#define NROW (BB*HH*SS)  // 65536
#define ROWSZ ((size_t)NROW * HD)  // 5,242,880 floats per tensor buffer

typedef unsigned short ushortT;
typedef __attribute__((ext_vector_type(8))) short bfrag;   // 8 bf16 = 4 VGPRs
typedef __attribute__((ext_vector_type(4))) float f4;
typedef __attribute__((ext_vector_type(4))) unsigned int u4;

__device__ __forceinline__ ushortT f2bf(float f) {
    __hip_bfloat16 h = __float2bfloat16(f);   // RNE
    ushortT u; __builtin_memcpy(&u, &h, 2); return u;
}
__device__ __forceinline__ float bf2f(ushortT u) {
    unsigned int x = ((unsigned int)u) << 16;
    float f; __builtin_memcpy(&f, &x, 4); return f;
}

// ---------------------------------------------------------------------------
// Kernel 0: prep — transpose + bf16-cast W1 (-> W1T[480][96], K zero-padded)
// and W2 (-> W2T[80][480]). Outputs live in d_out tail (k_mean overwrites last).
__global__ __launch_bounds__(256) void k_prep(const float* __restrict__ W1,
                                              const float* __restrict__ W2,
                                              ushortT* __restrict__ W1T,
                                              ushortT* __restrict__ W2T) {
    int idx = blockIdx.x * 256 + threadIdx.x;
    if (idx < 480 * 96) {
        int n = idx / 96, k = idx - n * 96;
        float v = (k < HD) ? W1[k * DH + n] : 0.f;
        W1T[idx] = f2bf(v);
    } else if (idx < 480 * 96 + 80 * 480) {
        int j = idx - 480 * 96;
        int n = j / DH, k = j - n * DH;
        W2T[j] = f2bf(W2[k * HD + n]);
    }
}

// ---------------------------------------------------------------------------
// Kernel 1: first LN. hdn stored as bf16 (every consumer casts to bf16 anyway);
// res stays fp32 (used in fp32 epilogue adds).
__global__ __launch_bounds__(256) void k_ln0(const float* __restrict__ x,
                                             const float* __restrict__ g,
                                             const float* __restrict__ be,
                                             ushortT* __restrict__ hdnb,
                                             float* __restrict__ res) {
    int row  = blockIdx.x * 4 + (threadIdx.x >> 6);
    int lane = threadIdx.x & 63;
    const float* xr = x + (size_t)row * HD;
    float v0 = xr[lane];
    float v1 = (lane < 16) ? xr[64 + lane] : 0.f;
    float s  = v0 + v1;
    float sq = v0 * v0 + v1 * v1;
#pragma unroll
    for (int o = 32; o; o >>= 1) { s += __shfl_xor(s, o); sq += __shfl_xor(sq, o); }
    float m    = s * (1.f / 80.f);
    float var  = sq * (1.f / 80.f) - m * m;
    float rstd = rsqrtf(var + 1e-5f);
    size_t base = (size_t)row * HD;
    float y0 = (v0 - m) * rstd * g[lane] + be[lane];
    hdnb[base + lane] = f2bf(y0); res[base + lane] = y0;
    if (lane < 16) {
        float y1 = (v1 - m) * rstd * g[64 + lane] + be[64 + lane];
        hdnb[base + 64 + lane] = f2bf(y1); res[base + 64 + lane] = y1;
    }
}

// ---------------------------------------------------------------------------
// Kernel 2: per-chunk intra attention + chunk KV, all via bf16 MFMA.
// Staging: u4 (16B) global reads, pure bit-copy into Xs (u4 store, r10-green
// pattern) + XT scatter via shift/mask (value ops only — no type punning).
__global__ __launch_bounds__(256) void k_attn_a(const ushortT* __restrict__ hdn,
                                                const float* __restrict__ slopes,
                                                float* __restrict__ oin,
                                                float* __restrict__ ckv) {
    __shared__ ushortT Xs[CC * 104];   // 128 rows x 96(k-pad, stride 104)
    __shared__ ushortT SC[CC * 40];    // 128 rows x 32(pad 40) score block, A-layout
    __shared__ ushortT XT[HD * 136];   // 80 d-rows x 128 j (stride 136)
    __shared__ float dec[CC];          // exp(-sl*delta)
    __shared__ float sqk[CC];          // sqrt(kd[j]) = exp(-0.5*sl*(128-j))

    int t    = threadIdx.x;
    int wave = t >> 6, lane = t & 63;
    int quad = lane >> 4, ln16 = lane & 15;
    int bk = blockIdx.x;
    int bh = bk >> 4;
    int n  = bk & 15;
    float sl = slopes[bh & 7];

    size_t chunkrow = (size_t)bh * SS + (size_t)n * CC;
    const ushortT* xb = hdn + chunkrow * HD;

    if (t < CC) {
        dec[t] = expf(-sl * (float)t);
        sqk[t] = expf(-0.5f * sl * (float)(CC - t));
    }
    // vectorized stage: 1280 u4 groups (8 bf16 each); row i = g/10, col = (g%10)*8
    {
        const u4* xin = (const u4*)xb;
        u4* Xs4 = (u4*)Xs;                       // Xs row = 13 u4
        for (int gq = t; gq < CC * 10; gq += 256) {
            int i = gq / 10, c8 = (gq - i * 10) * 8;
            u4 v = xin[gq];
            Xs4[i * 13 + (c8 >> 3)] = v;
#pragma unroll
            for (int z = 0; z < 4; ++z) {
                unsigned int w = v[z];
                XT[(c8 + 2 * z) * 136 + i]     = (ushortT)(w & 0xffffu);
                XT[(c8 + 2 * z + 1) * 136 + i] = (ushortT)(w >> 16);
            }
        }
        for (int u = t; u < CC * 16; u += 256) {
            int i = u >> 4, c = u & 15;
            Xs[i * 104 + 80 + c] = 0;
        }
    }
    __syncthreads();

    bfrag a[2][3];
#pragma unroll
    for (int rt = 0; rt < 2; ++rt) {
        int mt = wave + rt * 4;
#pragma unroll
        for (int ks = 0; ks < 3; ++ks)
            a[rt][ks] = *(const bfrag*)&Xs[(mt * 16 + ln16) * 104 + ks * 32 + quad * 8];
    }

    f4 oacc[2][5];
#pragma unroll
    for (int rt = 0; rt < 2; ++rt)
#pragma unroll
        for (int ot = 0; ot < 5; ++ot) oacc[rt][ot] = (f4)0.f;

    for (int jt = 0; jt < 4; ++jt) {
        if (wave + 4 < 2 * jt) continue;
        int j0 = jt * 32;
        bfrag bq[2][3];
#pragma unroll
        for (int nt = 0; nt < 2; ++nt)
#pragma unroll
            for (int ks = 0; ks < 3; ++ks)
                bq[nt][ks] = *(const bfrag*)&Xs[(j0 + nt * 16 + ln16) * 104 + ks * 32 + quad * 8];

#pragma unroll
        for (int rt = 0; rt < 2; ++rt) {
            int mt = wave + rt * 4;
            if (mt < 2 * jt) continue;
            int i_base = mt * 16;
            f4 c0 = (f4)0.f, c1 = (f4)0.f;
#pragma unroll
            for (int ks = 0; ks < 3; ++ks) {
                c0 = __builtin_amdgcn_mfma_f32_16x16x32_bf16(a[rt][ks], bq[0][ks], c0, 0, 0, 0);
                c1 = __builtin_amdgcn_mfma_f32_16x16x32_bf16(a[rt][ks], bq[1][ks], c1, 0, 0, 0);
            }
#pragma unroll
            for (int r = 0; r < 4; ++r) {
                int i = i_base + quad * 4 + r;
                int d0 = i - (j0 + ln16);
                int d1 = d0 - 16;
                float f0 = (d0 >= 0) ? dec[d0] : 0.f;
                float f1 = (d1 >= 0) ? dec[d1] : 0.f;
                SC[i * 40 + ln16]      = f2bf(c0[r] * f0);
                SC[i * 40 + 16 + ln16] = f2bf(c1[r] * f1);
            }
            bfrag a2 = *(const bfrag*)&SC[(i_base + ln16) * 40 + quad * 8];
#pragma unroll
            for (int ot = 0; ot < 5; ++ot) {
                bfrag bv = *(const bfrag*)&XT[(ot * 16 + ln16) * 136 + j0 + quad * 8];
                oacc[rt][ot] = __builtin_amdgcn_mfma_f32_16x16x32_bf16(a2, bv, oacc[rt][ot], 0, 0, 0);
            }
        }
    }

#pragma unroll
    for (int rt = 0; rt < 2; ++rt) {
        int i_base = (wave + rt * 4) * 16;
#pragma unroll
        for (int r = 0; r < 4; ++r) {
            size_t grow = (chunkrow + i_base + quad * 4 + r) * HD;
#pragma unroll
            for (int ot = 0; ot < 5; ++ot)
                oin[grow + ot * 16 + ln16] = oacc[rt][ot][r];
        }
    }

    __syncthreads();
    for (int u = t; u < HD * CC; u += 256) {
        int e = u >> 7, j = u & 127;
        int idx = e * 136 + j;
        XT[idx] = f2bf(bf2f(XT[idx]) * sqk[j]);
    }
    __syncthreads();

    float* kvout = ckv + (size_t)bk * (HD * HD);
    for (int p = wave; p < 25; p += 4) {
        int me = p / 5, ne = p - me * 5;
        f4 c = (f4)0.f;
#pragma unroll
        for (int ks = 0; ks < 4; ++ks) {
            bfrag av = *(const bfrag*)&XT[(me * 16 + ln16) * 136 + ks * 32 + quad * 8];
            bfrag bv = *(const bfrag*)&XT[(ne * 16 + ln16) * 136 + ks * 32 + quad * 8];
            c = __builtin_amdgcn_mfma_f32_16x16x32_bf16(av, bv, c, 0, 0, 0);
        }
#pragma unroll
        for (int r = 0; r < 4; ++r)
            kvout[(me * 16 + quad * 4 + r) * HD + ne * 16 + ln16] = c[r];
    }
}

// ---------------------------------------------------------------------------
// Kernel 3: in-place decay prefix-scan over chunk KVs. f4-vectorized: per-lane
// recurrence identical order -> bit-identical to the scalar version.
__global__ __launch_bounds__(256) void k_scan(float* __restrict__ kv,
                                              const float* __restrict__ slopes) {
    int idx = blockIdx.x * 256 + threadIdx.x;   // < 32*1600
    int bh  = idx / 1600;
    int ed  = idx - bh * 1600;
    float bd = expf(-slopes[bh & 7] * (float)CC);
    f4* kp = (f4*)kv;
    size_t base = (size_t)bh * NC * 1600 + ed;
    f4 st = (f4)0.f;
#pragma unroll
    for (int n = 0; n < NC; ++n) {
        size_t p = base + (size_t)n * 1600;
        f4 cv = kp[p];
        kp[p] = st;
        st = bd * st + cv;
    }
}

// ---------------------------------------------------------------------------
// Kernel 4: inter-chunk term via bf16 MFMA, fused + intra + residual + LN.
// (r10 version; KVT staging now f4-vectorized reads, same f2bf per element)
__global__ __launch_bounds__(256) void k_attn_b(const ushortT* __restrict__ hdn_in,
                                                const float* __restrict__ oin,
                                                const float* __restrict__ kvs,
                                                const float* __restrict__ res,
                                                const float* __restrict__ slopes,
                                                const float* __restrict__ g,
                                                const float* __restrict__ be,
                                                ushortT* __restrict__ hdn_out) {
    __shared__ ushortT Qs[CC * 104];     // 128 rows x (96 k, padded stride 104)
    __shared__ ushortT KVT[80 * 104];    // 80 d-rows x (96 e, padded stride 104)

    int t    = threadIdx.x;
    int wave = t >> 6, lane = t & 63;
    int qd   = lane >> 4, ln16 = lane & 15;
    int bk = blockIdx.x;
    int bh = bk >> 4;
    int n  = bk & 15;
    float sl = slopes[bh & 7];

    size_t chunkrow = (size_t)bh * SS + (size_t)n * CC;
    const ushortT* xb = hdn_in + chunkrow * HD;
    const float* KV = kvs + ((size_t)bh * NC + n) * (HD * HD);

    // Q staging: rows are 10 u4 (160B) each; Qs stride 104 ushorts = 13 u4.
    {
        const u4* xin = (const u4*)xb;
        u4* Qs4 = (u4*)Qs;
        for (int u = t; u < CC * 10; u += 256) {
            int i = u / 10, c = u - i * 10;
            Qs4[i * 13 + c] = xin[u];
        }
        for (int u = t; u < CC * 16; u += 256) {
            int i = u >> 4, c = u & 15;
            Qs[i * 104 + 80 + c] = 0;
        }
    }
    // KVT staging: f4 reads (1600 groups), scalar transposed bf16 stores.
    {
        const f4* kvin = (const f4*)KV;
        for (int gq = t; gq < 1600; gq += 256) {
            int e = gq / 20, d0 = (gq - e * 20) * 4;
            f4 v = kvin[gq];
#pragma unroll
            for (int z = 0; z < 4; ++z)
                KVT[(d0 + z) * 104 + e] = f2bf(v[z]);
        }
        for (int u = t; u < HD * 16; u += 256) {
            int d = u >> 4, e = u & 15;
            KVT[d * 104 + 80 + e] = 0;
        }
    }
    __syncthreads();

    int m0 = wave * 32;
    bfrag a[2][3];
#pragma unroll
    for (int rt = 0; rt < 2; ++rt)
#pragma unroll
        for (int ks = 0; ks < 3; ++ks)
            a[rt][ks] = *(const bfrag*)&Qs[(m0 + rt * 16 + ln16) * 104 + ks * 32 + qd * 8];

    f4 acc[2][5];
#pragma unroll
    for (int ot = 0; ot < 5; ++ot) {
#pragma unroll
        for (int rt = 0; rt < 2; ++rt) acc[rt][ot] = (f4)0.f;
#pragma unroll
        for (int ks = 0; ks < 3; ++ks) {
            bfrag b = *(const bfrag*)&KVT[(ot * 16 + ln16) * 104 + ks * 32 + qd * 8];
#pragma unroll
            for (int rt = 0; rt < 2; ++rt)
                acc[rt][ot] = __builtin_amdgcn_mfma_f32_16x16x32_bf16(a[rt][ks], b, acc[rt][ot], 0, 0, 0);
        }
    }

#pragma unroll
    for (int rt = 0; rt < 2; ++rt) {
#pragma unroll
        for (int r = 0; r < 4; ++r) {
            int i = m0 + rt * 16 + qd * 4 + r;
            float qdec = expf(-sl * (float)i);
            size_t grow = (chunkrow + i) * HD;
            float tv[5];
            float s = 0.f, sq = 0.f;
#pragma unroll
            for (int ot = 0; ot < 5; ++ot) {
                int col = ot * 16 + ln16;
                tv[ot] = oin[grow + col] + qdec * acc[rt][ot][r] + res[grow + col];
                s += tv[ot]; sq += tv[ot] * tv[ot];
            }
#pragma unroll
            for (int o = 8; o; o >>= 1) { s += __shfl_xor(s, o); sq += __shfl_xor(sq, o); }
            float m    = s * (1.f / 80.f);
            float var  = sq * (1.f / 80.f) - m * m;
            float rstd = rsqrtf(var + 1e-5f);
#pragma unroll
            for (int ot = 0; ot < 5; ++ot) {
                int col = ot * 16 + ln16;
                hdn_out[grow + col] = f2bf((tv[ot] - m) * rstd * g[col] + be[col]);
            }
        }
    }
}

// ---------------------------------------------------------------------------
// Kernel 5: FFN via bf16 MFMA, 128 rows/block. Input bf16 (u4-copy staging).
// Output: bf16 (iter 0, consumed by attn kernels) or fp32 (iter 1, k_mean).
// (byte-identical to round-10 green version)
__global__ __launch_bounds__(256, 2) void k_ffn(const ushortT* __restrict__ hdn_in,
                                                const ushortT* __restrict__ W1T,
                                                const float* __restrict__ b1,
                                                const ushortT* __restrict__ W2T,
                                                const float* __restrict__ b2,
                                                const float* __restrict__ res,
                                                const float* __restrict__ g,
                                                const float* __restrict__ be,
                                                ushortT* __restrict__ outb,
                                                float* __restrict__ outf,
                                                int write_f32) {
    __shared__ ushortT Xs[128 * 104];    // 26.6 KB: X tile, K padded 80->96
    __shared__ ushortT WH[128 * 104];    // 26.6 KB: W1 tile (rows 0..95) / Hs alias
    __shared__ ushortT W2s[80 * 104];    // 16.6 KB
    // total 69.9 KB -> 2 blocks/CU

    int t    = threadIdx.x;
    int wave = t >> 6, lane = t & 63;
    int qd   = lane >> 4, ln16 = lane & 15;
    size_t rowbase = (size_t)blockIdx.x * 128;

    // stage X: pure u4 copy (rows = 10 u4 of bf16; Xs stride 13 u4)
    {
        const u4* xin = (const u4*)(hdn_in + rowbase * HD);
        u4* Xs4 = (u4*)Xs;
        for (int u = t; u < 128 * 10; u += 256) {
            int i = u / 10, c = u - i * 10;
            Xs4[i * 13 + c] = xin[u];
        }
        for (int u = t; u < 128 * 16; u += 256) {
            int i = u >> 4, c = u & 15;
            Xs[i * 104 + 80 + c] = 0;
        }
    }

    f4 acc[2][5];
#pragma unroll
    for (int rt = 0; rt < 2; ++rt)
#pragma unroll
        for (int ot = 0; ot < 5; ++ot) acc[rt][ot] = (f4)0.f;

    const u4* W1T16 = (const u4*)W1T;    // 480 rows x 12 u4
    const u4* W2T16 = (const u4*)W2T;    // 80 rows x 60 u4
    u4* WH16  = (u4*)WH;                 // row stride 13 u4 (=104 ushort)
    u4* W2s16 = (u4*)W2s;

    for (int jt = 0; jt < DH; jt += 96) {
        __syncthreads();   // protects Xs (iter 0) / WH+W2s from previous iter reads
        for (int u = t; u < 96 * 12; u += 256) {
            int n = u / 12, k = u - n * 12;
            WH16[n * 13 + k] = W1T16[(size_t)(jt + n) * 12 + k];
        }
        for (int u = t; u < 80 * 12; u += 256) {
            int n = u / 12, k = u - n * 12;
            W2s16[n * 13 + k] = W2T16[(size_t)n * 60 + (jt >> 3) + k];
        }
        __syncthreads();

        // GEMM1: H chunk = X @ W1c. Each wave: 2 m-tiles (rows wave*32..+31)
        f4 hc[2][6];
#pragma unroll
        for (int rt = 0; rt < 2; ++rt)
#pragma unroll
            for (int nt = 0; nt < 6; ++nt) hc[rt][nt] = (f4)0.f;
#pragma unroll
        for (int ks = 0; ks < 3; ++ks) {
            bfrag a0 = *(const bfrag*)&Xs[((wave * 2 + 0) * 16 + ln16) * 104 + ks * 32 + qd * 8];
            bfrag a1 = *(const bfrag*)&Xs[((wave * 2 + 1) * 16 + ln16) * 104 + ks * 32 + qd * 8];
#pragma unroll
            for (int nt = 0; nt < 6; ++nt) {
                bfrag b = *(const bfrag*)&WH[(nt * 16 + ln16) * 104 + ks * 32 + qd * 8];
                hc[0][nt] = __builtin_amdgcn_mfma_f32_16x16x32_bf16(a0, b, hc[0][nt], 0, 0, 0);
                hc[1][nt] = __builtin_amdgcn_mfma_f32_16x16x32_bf16(a1, b, hc[1][nt], 0, 0, 0);
            }
        }
        __syncthreads();   // all waves done reading W1 tile (WH) before Hs overwrite

        // leaky-relu + bf16 -> Hs (aliases WH; rows wave-private)
#pragma unroll
        for (int rt = 0; rt < 2; ++rt) {
            int mrow = (wave * 2 + rt) * 16 + qd * 4;
#pragma unroll
            for (int nt = 0; nt < 6; ++nt) {
                float bv = b1[jt + nt * 16 + ln16];
#pragma unroll
                for (int r = 0; r < 4; ++r) {
                    float v = hc[rt][nt][r] + bv;
                    v = (v > 0.f) ? v : 0.01f * v;
                    WH[(mrow + r) * 104 + nt * 16 + ln16] = f2bf(v);
                }
            }
        }
        // GEMM2: acc += H chunk @ W2c (no barrier: Hs rows written by this wave)
#pragma unroll
        for (int ks = 0; ks < 3; ++ks) {
            bfrag a0 = *(const bfrag*)&WH[((wave * 2 + 0) * 16 + ln16) * 104 + ks * 32 + qd * 8];
            bfrag a1 = *(const bfrag*)&WH[((wave * 2 + 1) * 16 + ln16) * 104 + ks * 32 + qd * 8];
#pragma unroll
            for (int ot = 0; ot < 5; ++ot) {
                bfrag b = *(const bfrag*)&W2s[(ot * 16 + ln16) * 104 + ks * 32 + qd * 8];
                acc[0][ot] = __builtin_amdgcn_mfma_f32_16x16x32_bf16(a0, b, acc[0][ot], 0, 0, 0);
                acc[1][ot] = __builtin_amdgcn_mfma_f32_16x16x32_bf16(a1, b, acc[1][ot], 0, 0, 0);
            }
        }
    }

    // epilogue: + b2 + residual, LN per row (C-layout: row=qd*4+r, col=ot*16+ln16)
#pragma unroll
    for (int rt = 0; rt < 2; ++rt) {
        int mbase = (wave * 2 + rt) * 16 + qd * 4;
#pragma unroll
        for (int r = 0; r < 4; ++r) {
            size_t row = rowbase + mbase + r;
            float tv[5];
            float s = 0.f, sq = 0.f;
#pragma unroll
            for (int ot = 0; ot < 5; ++ot) {
                int col = ot * 16 + ln16;
                tv[ot] = acc[rt][ot][r] + b2[col] + res[row * HD + col];
                s += tv[ot]; sq += tv[ot] * tv[ot];
            }
#pragma unroll
            for (int o = 8; o; o >>= 1) { s += __shfl_xor(s, o); sq += __shfl_xor(sq, o); }
            float m    = s * (1.f / 80.f);
            float var  = sq * (1.f / 80.f) - m * m;
            float rstd = rsqrtf(var + 1e-5f);
            if (write_f32) {
#pragma unroll
                for (int ot = 0; ot < 5; ++ot) {
                    int col = ot * 16 + ln16;
                    outf[row * HD + col] = (tv[ot] - m) * rstd * g[col] + be[col];
                }
            } else {
#pragma unroll
                for (int ot = 0; ot < 5; ++ot) {
                    int col = ot * 16 + ln16;
                    outb[row * HD + col] = f2bf((tv[ot] - m) * rstd * g[col] + be[col]);
                }
            }
        }
    }
}

// ---------------------------------------------------------------------------
// Kernel 6: mean over heads -> (B, S, HD). f4-vectorized (green in r11).
__global__ __launch_bounds__(256) void k_mean(const float* __restrict__ hdn,
                                              float* __restrict__ out) {
    int idx = blockIdx.x * 256 + threadIdx.x;      // < BB*SS*HD/4
    int b   = idx / (SS * HD / 4);
    int sd  = idx - b * (SS * HD / 4);
    const f4* hp = (const f4*)hdn;
    f4 s = (f4)0.f;
#pragma unroll
    for (int h = 0; h < HH; ++h) {
        f4 v = hp[(size_t)(b * HH + h) * (SS * HD / 4) + sd];
        s = s + v;
    }
    ((f4*)out)[idx] = s * 0.125f;
}

// ---------------------------------------------------------------------------
extern "C" void kernel_launch(void* const* d_in, const int* in_sizes, int n_in,
                              void* d_out, int out_size, void* d_ws, size_t ws_size,
                              hipStream_t stream) {
    (void)in_sizes; (void)n_in; (void)out_size; (void)ws_size;
    const float* x      = (const float*)d_in[0];
    const float* W1     = (const float*)d_in[1];
    const float* b1     = (const float*)d_in[2];
    const float* W2     = (const float*)d_in[3];
    const float* b2     = (const float*)d_in[4];
    const float* gamma  = (const float*)d_in[5];
    const float* beta   = (const float*)d_in[6];
    const float* slopes = (const float*)d_in[7];
    float* out = (float*)d_out;
    float* ws  = (float*)d_ws;

    float*   res  = ws;                          // fp32, 5,242,880 floats
    ushortT* hdnb = (ushortT*)(ws + ROWSZ);      // bf16 hdn intermediates
    float*   oin  = ws + 2 * ROWSZ;              // fp32 (precision-critical)
    float*   kv   = ws + 3 * ROWSZ;              // fp32, 3,276,800
    float*   hdnf = ws + 4 * ROWSZ;              // fp32 final (k_mean input)

    // bf16 transposed weights live in d_out scratch (k_mean overwrites it last)
    ushortT* W1T = (ushortT*)d_out;              // 480*96
    ushortT* W2T = W1T + 480 * 96;               // 80*480

    k_prep<<<(480 * 96 + 80 * 480 + 255) / 256, 256, 0, stream>>>(W1, W2, W1T, W2T);
    k_ln0<<<NROW / 4, 256, 0, stream>>>(x, gamma, beta, hdnb, res);
    for (int it = 0; it < 2; ++it) {
        k_attn_a<<<BB * HH * NC, 256, 0, stream>>>(hdnb, slopes, oin, kv);
        k_scan<<<(BB * HH * HD * HD / 4) / 256, 256, 0, stream>>>(kv, slopes);
        k_attn_b<<<BB * HH * NC, 256, 0, stream>>>(hdnb, oin, kv, res, slopes, gamma, beta, hdnb);
        k_ffn<<<NROW / 128, 256, 0, stream>>>(hdnb, W1T, b1, W2T, b2, res, gamma, beta,
                                              hdnb, hdnf, (it == 1) ? 1 : 0);
    }
    k_mean<<<(BB * SS * HD) / (256 * 4), 256, 0, stream>>>(hdnf, out);
}